// Round 2
// baseline (71.636 us; speedup 1.0000x reference)
//
#include <hip/hip_runtime.h>

// Geometry (fixed by the reference)
#define FDIM 16
#define SDIM 512
#define ODIM 32
#define SF   (SDIM * FDIM)   // 8192 floats per batch row
#define PAIRS 512            // (f,o) pairs; W[s*512 + p], p = f*32+o
#define NB   8               // batches per block (W reuse factor)
#define SC   32              // shifts per block
#define NSC  (SDIM / SC)     // 16 s-chunks
#define NBG  (256 / NB)      // 32 batch groups

// Phase 1: partial max over an s-chunk, for NB batches x all 512 pairs.
// Thread tq (=t&127) owns pairs 4tq..4tq+3 (one f); th (=t>>7) splits the
// 32-s chunk in half. Each W float4 is loaded ONCE and reused across the
// NB=8 batch accumulators -> W L2 traffic = (256/NB) MB = 32 MB total.
//
// XCD-locality swizzle (index bijection only): all 16 s-chunks of batch
// groups {4x..4x+3} land on blocks with bid%8 == x, so the partials for
// batches [32x,32x+32) (1 MB) stay dirty in XCD x's L2. Phase 2 reads them
// from the same XCD.
__global__ __launch_bounds__(256) void max_layer_phase1(
    const float* __restrict__ x, const float* __restrict__ W,
    float* __restrict__ part) {
  __shared__ float xs[NB * SC * FDIM];  // 16 KB, [b][s][f]
  __shared__ float red[NB * PAIRS];     // 16 KB, th=1 partials

  const int t   = threadIdx.x;
  const int bid = blockIdx.x;
  const int sc  = bid >> 5;                   // 0..15
  const int r   = bid & 31;
  const int bg  = ((r & 7) << 2) | (r >> 3);  // bijection; bg/4 == bid%8

  // Stage x chunk: per b, 2 KB contiguous; fully coalesced float4.
  const float4* xin = (const float4*)x;
  float4* xs4 = (float4*)xs;
  for (int i = t; i < NB * SC * FDIM / 4; i += 256) {
    int b   = i / (SC * FDIM / 4);   // /128
    int off = i % (SC * FDIM / 4);
    xs4[i] = xin[(size_t)(bg * NB + b) * (SF / 4) + sc * (SC * FDIM / 4) + off];
  }
  __syncthreads();

  const int tq = t & 127;
  const int th = t >> 7;          // s-half 0/1
  const int f  = tq >> 3;         // f of owned pairs

  const float NEG = -3.402823466e+38f;
  float4 macc[NB];
#pragma unroll
  for (int b = 0; b < NB; ++b) macc[b] = make_float4(NEG, NEG, NEG, NEG);

  const float4* wp = (const float4*)W + (size_t)(sc * SC) * (PAIRS / 4) + tq;

#pragma unroll 4
  for (int j = 0; j < SC / 2; ++j) {
    const int s = th * (SC / 2) + j;
    float4 w = wp[s * (PAIRS / 4)];      // one 2KB W row / s, shared by 2 waves
    const float* xp = xs + s * FDIM + f;
#pragma unroll
    for (int b = 0; b < NB; ++b) {
      float xv = xp[b * SC * FDIM];      // LDS broadcast (8 lanes/addr)
      macc[b].x = fmaxf(macc[b].x, xv * w.x);
      macc[b].y = fmaxf(macc[b].y, xv * w.y);
      macc[b].z = fmaxf(macc[b].z, xv * w.z);
      macc[b].w = fmaxf(macc[b].w, xv * w.w);
    }
  }

  // Combine the two s-halves, write partials: part[(b)*NSC + sc][p]
  if (th == 1) {
#pragma unroll
    for (int b = 0; b < NB; ++b) ((float4*)red)[b * 128 + tq] = macc[b];
  }
  __syncthreads();
  if (th == 0) {
#pragma unroll
    for (int b = 0; b < NB; ++b) {
      float4 o = ((float4*)red)[b * 128 + tq];
      o.x = fmaxf(o.x, macc[b].x);
      o.y = fmaxf(o.y, macc[b].y);
      o.z = fmaxf(o.z, macc[b].z);
      o.w = fmaxf(o.w, macc[b].w);
      ((float4*)part)[((size_t)(bg * NB + b) * NSC + sc) * (PAIRS / 4) + tq] = o;
    }
  }
}

// Phase 2: max over the 16 chunk-partials per (b,p), then f-sum + bias + relu.
// Block for batch b runs on XCD b/32 (bid%8 heuristic) == the XCD whose L2
// holds b's partials. t<128 threads each reduce one float4 column over the
// 16 chunks (independent loads -> deep VMEM pipeline), red[] keeps the
// round-0 float layout so the f-sum epilogue is unchanged.
__global__ __launch_bounds__(256) void max_layer_phase2(
    const float* __restrict__ part, const float* __restrict__ bias,
    float* __restrict__ out) {
  __shared__ float red[PAIRS];
  const int t   = threadIdx.x;
  const int bid = blockIdx.x;
  const int b   = ((bid & 7) << 5) | (bid >> 3);   // bijection; b/32 == bid%8

  const float4* pb = (const float4*)part + (size_t)b * NSC * (PAIRS / 4);
  if (t < 128) {
    float4 m = pb[t];
#pragma unroll
    for (int c = 1; c < NSC; ++c) {
      float4 v = pb[c * (PAIRS / 4) + t];
      m.x = fmaxf(m.x, v.x);
      m.y = fmaxf(m.y, v.y);
      m.z = fmaxf(m.z, v.z);
      m.w = fmaxf(m.w, v.w);
    }
    ((float4*)red)[t] = m;
  }
  __syncthreads();
  if (t < ODIM) {
    float s = bias[t];
#pragma unroll
    for (int ff = 0; ff < FDIM; ++ff) s += red[ff * ODIM + t];
    out[b * ODIM + t] = fmaxf(s, 0.0f);
  }
}

extern "C" void kernel_launch(void* const* d_in, const int* in_sizes, int n_in,
                              void* d_out, int out_size, void* d_ws, size_t ws_size,
                              hipStream_t stream) {
  const float* x    = (const float*)d_in[0];
  const float* W    = (const float*)d_in[1];
  const float* bias = (const float*)d_in[2];
  float* out        = (float*)d_out;
  float* part       = (float*)d_ws;   // 256*16*512*4 = 8 MB of scratch

  max_layer_phase1<<<dim3(NBG * NSC), dim3(256), 0, stream>>>(x, W, part);
  max_layer_phase2<<<dim3(256), dim3(256), 0, stream>>>(part, bias, out);
}